// Round 11
// baseline (123.454 us; speedup 1.0000x reference)
//
#include <hip/hip_runtime.h>

// GPLoss: gradient-profile loss, scalar output.
// Main pass: 1536 blocks x 256 thr; block = one 32-row band of one plane.
// Wave w owns rows [q*32+8w, +8) + 1 halo row; lane owns 8 FULL-ROW cols
// (2 x float4 per array). Row stats: one wave spans the whole row -> 6 DPP
// chains complete the row sum in-wave (lane 63), cos in-register, NO rowbuf.
// f_v halo col = shfl_down(neighbor lane's first col) -> zero halo VMEM.
// Col stats: 48 per-thread accums -> 2-buffer LDS merge -> colPart slot
// (96*16 slots = 18.9 MB, the L3-safe round-8 layout, regular stores).
// ws: colPart f32[96*16][6][512] ; rowPart f32[1536*4][2] ; dblk f64[192]

typedef float f32x4 __attribute__((ext_vector_type(4)));

#define DPP_ADD(x, ctrl, rmask) \
  x += __int_as_float(__builtin_amdgcn_update_dpp(0, __float_as_int(x), ctrl, rmask, 0xf, false))

__device__ __forceinline__ float wave_dpp_sum(float x){
  DPP_ADD(x, 0x111, 0xf);   // row_shr:1
  DPP_ADD(x, 0x112, 0xf);   // row_shr:2
  DPP_ADD(x, 0x114, 0xf);   // row_shr:4
  DPP_ADD(x, 0x118, 0xf);   // row_shr:8
  DPP_ADD(x, 0x142, 0xa);   // row_bcast:15 -> rows 1,3
  DPP_ADD(x, 0x143, 0xc);   // row_bcast:31 -> rows 2,3
  return x;                 // lane 63 holds the 64-lane sum
}

__device__ __forceinline__ float cos_sim(float d, float sx, float sr){
  float nx = fmaxf(sqrtf(sx), 1e-12f);
  float nr = fmaxf(sqrtf(sr), 1e-12f);
  return d / (nx * nr);
}

__global__ __launch_bounds__(256, 4) void gp_uni(
    const float* __restrict__ X, const float* __restrict__ R,
    float* __restrict__ rowPart, float* __restrict__ colPart)
{
  const int bid = blockIdx.x;
  const int p = bid >> 4, q = bid & 15;        // plane, 32-row band
  const int tid = threadIdx.x, w = tid >> 6, l = tid & 63;
  const size_t plane = (size_t)p * (512u * 512u);
  const float* xp = X + plane;
  const float* rp = R + plane;
  const int c = 8 * l;                          // cols c..c+7 (full row/wave)
  const bool tlast = (l == 63);                 // col 511: no f_v
  const int h0 = q*32 + w*8;                    // first row of this wave

  __shared__ float Abuf[6][512];                // 12 KB (waves 0,1)
  __shared__ float Bbuf[6][512];                // 12 KB (waves 2,3)

  float cv0[8], cv1[8], cv2[8], ch0[8], ch1[8], ch2[8];
  #pragma unroll
  for (int j = 0; j < 8; ++j){
    cv0[j]=0.f; cv1[j]=0.f; cv2[j]=0.f;
    ch0[j]=0.f; ch1[j]=0.f; ch2[j]=0.f;
  }
  float rsv = 0.f, rsh = 0.f;                   // valid on lane 63

  const float* xr = xp + (size_t)h0*512 + c;
  const float* rr = rp + (size_t)h0*512 + c;
  float4 xa = *(const float4*)xr, xb = *(const float4*)(xr+4);
  float4 ra = *(const float4*)rr, rb = *(const float4*)(rr+4);

  #pragma unroll 2
  for (int k = 0; k < 8; ++k){
    const int h  = h0 + k;
    const int hn = (h+1 < 512) ? h+1 : 511;     // h==511: next==cur -> dh=0
    const float* xn = xp + (size_t)hn*512 + c;
    const float* rn = rp + (size_t)hn*512 + c;
    const float4 nxa = *(const float4*)xn, nxb = *(const float4*)(xn+4);
    const float4 nra = *(const float4*)rn, nrb = *(const float4*)(rn+4);

    // f_v halo: lane l needs col 8l+8 = lane (l+1)'s xa.x (LDS pipe, idle)
    const float xhalo = __shfl_down(xa.x, 1, 64);
    const float rhalo = __shfl_down(ra.x, 1, 64);

    const float ax[8] = {xa.x,xa.y,xa.z,xa.w, xb.x,xb.y,xb.z,xb.w};
    const float ar[8] = {ra.x,ra.y,ra.z,ra.w, rb.x,rb.y,rb.z,rb.w};
    const float bx[8] = {nxa.x,nxa.y,nxa.z,nxa.w, nxb.x,nxb.y,nxb.z,nxb.w};
    const float br[8] = {nra.x,nra.y,nra.z,nra.w, nrb.x,nrb.y,nrb.z,nrb.w};

    float p0=0.f,p1=0.f,p2=0.f, q0=0.f,q1=0.f,q2=0.f;
    #pragma unroll
    for (int j = 0; j < 8; ++j){
      const float dv = (j<7) ? (ax[j]-ax[j+1]) : (tlast ? 0.f : (ax[7]-xhalo));
      const float ev = (j<7) ? (ar[j]-ar[j+1]) : (tlast ? 0.f : (ar[7]-rhalo));
      p0 = fmaf(dv,ev,p0); p1 = fmaf(dv,dv,p1); p2 = fmaf(ev,ev,p2);
      cv0[j] = fmaf(dv,ev,cv0[j]);
      cv1[j] = fmaf(dv,dv,cv1[j]);
      cv2[j] = fmaf(ev,ev,cv2[j]);
      const float dh = ax[j]-bx[j];
      const float eh = ar[j]-br[j];
      q0 = fmaf(dh,eh,q0); q1 = fmaf(dh,dh,q1); q2 = fmaf(eh,eh,q2);
      ch0[j] = fmaf(dh,eh,ch0[j]);
      ch1[j] = fmaf(dh,dh,ch1[j]);
      ch2[j] = fmaf(eh,eh,ch2[j]);
    }

    // full-row reduction: 6 independent DPP chains, sum lands in lane 63
    p0 = wave_dpp_sum(p0); p1 = wave_dpp_sum(p1); p2 = wave_dpp_sum(p2);
    q0 = wave_dpp_sum(q0); q1 = wave_dpp_sum(q1); q2 = wave_dpp_sum(q2);
    rsv += cos_sim(p0,p1,p2);                 // garbage on lanes<63, unused
    if (h < 511) rsh += cos_sim(q0,q1,q2);

    xa = nxa; xb = nxb; ra = nra; rb = nrb;
  }

  // ---- col merge: w0->A, w2->B ; then w1+=A, w3+=B ; then store A+B
  if (w == 0){
    #pragma unroll
    for (int j = 0; j < 8; ++j){
      Abuf[0][c+j]=cv0[j]; Abuf[1][c+j]=cv1[j]; Abuf[2][c+j]=cv2[j];
      Abuf[3][c+j]=ch0[j]; Abuf[4][c+j]=ch1[j]; Abuf[5][c+j]=ch2[j];
    }
  } else if (w == 2){
    #pragma unroll
    for (int j = 0; j < 8; ++j){
      Bbuf[0][c+j]=cv0[j]; Bbuf[1][c+j]=cv1[j]; Bbuf[2][c+j]=cv2[j];
      Bbuf[3][c+j]=ch0[j]; Bbuf[4][c+j]=ch1[j]; Bbuf[5][c+j]=ch2[j];
    }
  }
  __syncthreads();
  if (w == 1){
    #pragma unroll
    for (int j = 0; j < 8; ++j){
      Abuf[0][c+j]+=cv0[j]; Abuf[1][c+j]+=cv1[j]; Abuf[2][c+j]+=cv2[j];
      Abuf[3][c+j]+=ch0[j]; Abuf[4][c+j]+=ch1[j]; Abuf[5][c+j]+=ch2[j];
    }
  } else if (w == 3){
    #pragma unroll
    for (int j = 0; j < 8; ++j){
      Bbuf[0][c+j]+=cv0[j]; Bbuf[1][c+j]+=cv1[j]; Bbuf[2][c+j]+=cv2[j];
      Bbuf[3][c+j]+=ch0[j]; Bbuf[4][c+j]+=ch1[j]; Bbuf[5][c+j]+=ch2[j];
    }
  }
  __syncthreads();
  {
    const f32x4* A4 = (const f32x4*)Abuf;
    const f32x4* B4 = (const f32x4*)Bbuf;
    f32x4* s4 = (f32x4*)(colPart + (size_t)bid * (6*512));
    #pragma unroll
    for (int i = 0; i < 3; ++i)
      s4[tid + 256*i] = A4[tid + 256*i] + B4[tid + 256*i];
  }

  if (l == 63){
    rowPart[(bid*4 + w)*2 + 0] = rsv;
    rowPart[(bid*4 + w)*2 + 1] = rsh;
  }
}

// ---------------- finish: reduce col partials over 16 slots ------------------
__global__ __launch_bounds__(256) void gp_cols(
    const float* __restrict__ colPart, double* __restrict__ dblk)
{
  const int p = blockIdx.x >> 1;
  const int f = blockIdx.x & 1;    // 0 = fv, 1 = fh
  const int tid = threadIdx.x;
  double acc = 0.0;
  for (int c = tid; c < 512; c += 256){
    float d = 0.f, a = 0.f, b = 0.f;
    #pragma unroll
    for (int s = 0; s < 16; ++s){
      const float* sp = colPart + ((size_t)(p*16 + s) * 6 + f*3) * 512;
      d += sp[c]; a += sp[512 + c]; b += sp[1024 + c];
    }
    acc += (double)cos_sim(d, a, b);   // fv col 511: cos(0,0,0)=0, harmless
  }
  #pragma unroll
  for (int m = 1; m < 64; m <<= 1) acc += __shfl_xor(acc, m, 64);
  __shared__ double ls[4];
  const int w = tid >> 6, l = tid & 63;
  if (l == 0) ls[w] = acc;
  __syncthreads();
  if (tid == 0) dblk[blockIdx.x] = ls[0] + ls[1] + ls[2] + ls[3];
}

__global__ __launch_bounds__(256) void gp_fin(
    const double* __restrict__ dblk, const float* __restrict__ rowPart,
    int nblk, float* __restrict__ out)
{
  const int tid = threadIdx.x;
  double rv = 0, rh = 0, cv = 0, ch = 0;
  for (int i = tid; i < nblk; i += 256){
    rv += (double)rowPart[2*i];
    rh += (double)rowPart[2*i+1];
  }
  for (int i = tid; i < 192; i += 256){
    if (i & 1) ch += dblk[i]; else cv += dblk[i];
  }
  #pragma unroll
  for (int m = 1; m < 64; m <<= 1){
    rv += __shfl_xor(rv, m, 64); rh += __shfl_xor(rh, m, 64);
    cv += __shfl_xor(cv, m, 64); ch += __shfl_xor(ch, m, 64);
  }
  __shared__ double ls[4][4];
  const int w = tid >> 6, l = tid & 63;
  if (l == 0){ ls[w][0]=rv; ls[w][1]=rh; ls[w][2]=cv; ls[w][3]=ch; }
  __syncthreads();
  if (tid == 0){
    double RV=0, RH=0, CV=0, CH=0;
    #pragma unroll
    for (int i = 0; i < 4; ++i){ RV+=ls[i][0]; RH+=ls[i][1]; CV+=ls[i][2]; CH+=ls[i][3]; }
    const double t = RV/512.0 + RH/511.0 + CV/511.0 + CH/512.0;
    out[0] = (float)(-t / 32.0);
  }
}

extern "C" void kernel_launch(void* const* d_in, const int* in_sizes, int n_in,
                              void* d_out, int out_size, void* d_ws, size_t ws_size,
                              hipStream_t stream) {
  const float* X = (const float*)d_in[0];
  const float* R = (const float*)d_in[1];
  float* out = (float*)d_out;

  float*  colPart = (float*)d_ws;                           // 96*16*6*512 f32
  float*  rowPart = colPart + (size_t)96*16*6*512;          // 6144*2 f32
  double* dblk    = (double*)(rowPart + (size_t)6144*2);    // 192 f64

  gp_uni <<<dim3(1536), dim3(256), 0, stream>>>(X, R, rowPart, colPart);
  gp_cols<<<dim3(192),  dim3(256), 0, stream>>>(colPart, dblk);
  gp_fin <<<dim3(1),    dim3(256), 0, stream>>>(dblk, rowPart, 6144, out);
}

// Round 12
// 53.646 us; speedup vs baseline: 2.3012x; 2.3012x over previous
//
#include <hip/hip_runtime.h>

// GPLoss: gradient-profile loss, scalar output.
// Main pass (round-8 structure + dual row-streams): 1536 blocks x 256 thr;
// block = one 32-row band-pair. Wave (half,wp): rows [h0,h0+16) x 256 cols,
// lane owns 4 cols (float4). DUAL streams: rows h0+k (A) and h0+8+k (B) --
// two independent load->compute->DPP chains => 2x loads in flight.
// Row stats: 12 DPP chains/iter (VALU pipe) -> rowbuf; col stats: 24 regs
// -> 2-phase LDS merge -> colPart slot (96*16 = 18.9 MB, L3-safe: inputs
// stay resident across timed replays). VGPR discipline: ~75 live (cliff=64,
// spill tripwire = WRITE_SIZE >> 19 MB).
// ws: colPart f32[96*16][6][512] ; rowPart f32[1536][2] ; dblk f64[192]

typedef float f32x4 __attribute__((ext_vector_type(4)));

#define DPP_ADD(x, ctrl, rmask) \
  x += __int_as_float(__builtin_amdgcn_update_dpp(0, __float_as_int(x), ctrl, rmask, 0xf, false))

__device__ __forceinline__ float wave_dpp_sum(float x){
  DPP_ADD(x, 0x111, 0xf);   // row_shr:1
  DPP_ADD(x, 0x112, 0xf);   // row_shr:2
  DPP_ADD(x, 0x114, 0xf);   // row_shr:4
  DPP_ADD(x, 0x118, 0xf);   // row_shr:8
  DPP_ADD(x, 0x142, 0xa);   // row_bcast:15 -> rows 1,3
  DPP_ADD(x, 0x143, 0xc);   // row_bcast:31 -> rows 2,3
  return x;                 // lane 63 holds the 64-lane sum
}

__device__ __forceinline__ float cos_sim(float d, float sx, float sr){
  float nx = fmaxf(sqrtf(sx), 1e-12f);
  float nr = fmaxf(sqrtf(sr), 1e-12f);
  return d / (nx * nr);
}

__global__ __launch_bounds__(256) void gp_uni(
    const float* __restrict__ X, const float* __restrict__ R,
    float* __restrict__ rowPart, float* __restrict__ colPart)
{
  const int bid = blockIdx.x;
  const int p = bid >> 4, q = bid & 15;        // plane, 32-row band-pair
  const int tid = threadIdx.x, w = tid >> 6, l = tid & 63;
  const int half = w >> 1;                      // rows [h0, h0+16)
  const int wp   = w & 1;                       // col half: wp*256
  const size_t plane = (size_t)p * (512u * 512u);
  const float* xp = X + plane;
  const float* rp = R + plane;
  const int c  = wp*256 + 4*l;                  // cols c..c+3
  const int cn = (c+4 < 512) ? c+4 : 511;       // f_v halo col (clamped)
  const bool tlast = (c == 508);                // col 511: no f_v
  const int h0 = q*32 + half*16;                // A: h0+k ; B: h0+8+k

  __shared__ float colbuf[6][512];              // 12 KB band merge
  __shared__ float rowbuf[32][2][6];            // 1.5 KB row stats

  float cv0[4], cv1[4], cv2[4], ch0[4], ch1[4], ch2[4];
  #pragma unroll
  for (int j = 0; j < 4; ++j){
    cv0[j]=0.f; cv1[j]=0.f; cv2[j]=0.f;
    ch0[j]=0.f; ch1[j]=0.f; ch2[j]=0.f;
  }

  const float* xA0 = xp + (size_t)h0*512;
  const float* rA0 = rp + (size_t)h0*512;
  const float* xB0 = xp + (size_t)(h0+8)*512;
  const float* rB0 = rp + (size_t)(h0+8)*512;
  float4 xcA = *(const float4*)(xA0 + c), rcA = *(const float4*)(rA0 + c);
  float4 xcB = *(const float4*)(xB0 + c), rcB = *(const float4*)(rB0 + c);
  float  xhA = xA0[cn], rhA = rA0[cn];
  float  xhB = xB0[cn], rhB = rB0[cn];

  for (int k = 0; k < 8; ++k){
    const int hA  = h0 + k;                     // <= 510 always
    const int hB  = h0 + 8 + k;
    const int hnB = (hB+1 < 512) ? hB+1 : 511;  // hB==511: next==cur -> dh=0

    // issue BOTH streams' next-row loads up front (independent of compute)
    const float* xAn = xp + (size_t)(hA+1)*512;
    const float* rAn = rp + (size_t)(hA+1)*512;
    const float* xBn = xp + (size_t)hnB*512;
    const float* rBn = rp + (size_t)hnB*512;
    const float4 nxA = *(const float4*)(xAn + c), nrA = *(const float4*)(rAn + c);
    const float4 nxB = *(const float4*)(xBn + c), nrB = *(const float4*)(rBn + c);
    const float  nxhA = xAn[cn], nrhA = rAn[cn];
    const float  nxhB = xBn[cn], nrhB = rBn[cn];

    // ---------------- stream A ----------------
    float pA0=0.f,pA1=0.f,pA2=0.f, qA0=0.f,qA1=0.f,qA2=0.f;
    {
      const float ax[4] = {xcA.x, xcA.y, xcA.z, xcA.w};
      const float ar[4] = {rcA.x, rcA.y, rcA.z, rcA.w};
      const float bx[4] = {nxA.x, nxA.y, nxA.z, nxA.w};
      const float br[4] = {nrA.x, nrA.y, nrA.z, nrA.w};
      float dv[4], ev[4];
      dv[0]=ax[0]-ax[1]; dv[1]=ax[1]-ax[2]; dv[2]=ax[2]-ax[3];
      ev[0]=ar[0]-ar[1]; ev[1]=ar[1]-ar[2]; ev[2]=ar[2]-ar[3];
      dv[3] = tlast ? 0.f : (ax[3]-xhA);
      ev[3] = tlast ? 0.f : (ar[3]-rhA);
      #pragma unroll
      for (int j = 0; j < 4; ++j){
        pA0 = fmaf(dv[j],ev[j],pA0); pA1 = fmaf(dv[j],dv[j],pA1); pA2 = fmaf(ev[j],ev[j],pA2);
        cv0[j] = fmaf(dv[j],ev[j],cv0[j]);
        cv1[j] = fmaf(dv[j],dv[j],cv1[j]);
        cv2[j] = fmaf(ev[j],ev[j],cv2[j]);
        const float dh = ax[j]-bx[j];
        const float eh = ar[j]-br[j];
        qA0 = fmaf(dh,eh,qA0); qA1 = fmaf(dh,dh,qA1); qA2 = fmaf(eh,eh,qA2);
        ch0[j] = fmaf(dh,eh,ch0[j]);
        ch1[j] = fmaf(dh,dh,ch1[j]);
        ch2[j] = fmaf(eh,eh,ch2[j]);
      }
    }

    // ---------------- stream B ----------------
    float pB0=0.f,pB1=0.f,pB2=0.f, qB0=0.f,qB1=0.f,qB2=0.f;
    {
      const float ax[4] = {xcB.x, xcB.y, xcB.z, xcB.w};
      const float ar[4] = {rcB.x, rcB.y, rcB.z, rcB.w};
      const float bx[4] = {nxB.x, nxB.y, nxB.z, nxB.w};
      const float br[4] = {nrB.x, nrB.y, nrB.z, nrB.w};
      float dv[4], ev[4];
      dv[0]=ax[0]-ax[1]; dv[1]=ax[1]-ax[2]; dv[2]=ax[2]-ax[3];
      ev[0]=ar[0]-ar[1]; ev[1]=ar[1]-ar[2]; ev[2]=ar[2]-ar[3];
      dv[3] = tlast ? 0.f : (ax[3]-xhB);
      ev[3] = tlast ? 0.f : (ar[3]-rhB);
      #pragma unroll
      for (int j = 0; j < 4; ++j){
        pB0 = fmaf(dv[j],ev[j],pB0); pB1 = fmaf(dv[j],dv[j],pB1); pB2 = fmaf(ev[j],ev[j],pB2);
        cv0[j] = fmaf(dv[j],ev[j],cv0[j]);
        cv1[j] = fmaf(dv[j],dv[j],cv1[j]);
        cv2[j] = fmaf(ev[j],ev[j],cv2[j]);
        const float dh = ax[j]-bx[j];
        const float eh = ar[j]-br[j];
        qB0 = fmaf(dh,eh,qB0); qB1 = fmaf(dh,dh,qB1); qB2 = fmaf(eh,eh,qB2);
        ch0[j] = fmaf(dh,eh,ch0[j]);
        ch1[j] = fmaf(dh,dh,ch1[j]);
        ch2[j] = fmaf(eh,eh,ch2[j]);
      }
    }

    // ---- 12 independent DPP chains (VALU pipe)
    pA0 = wave_dpp_sum(pA0); pA1 = wave_dpp_sum(pA1); pA2 = wave_dpp_sum(pA2);
    qA0 = wave_dpp_sum(qA0); qA1 = wave_dpp_sum(qA1); qA2 = wave_dpp_sum(qA2);
    pB0 = wave_dpp_sum(pB0); pB1 = wave_dpp_sum(pB1); pB2 = wave_dpp_sum(pB2);
    qB0 = wave_dpp_sum(qB0); qB1 = wave_dpp_sum(qB1); qB2 = wave_dpp_sum(qB2);
    if (l == 63){
      const int rA_ = half*16 + k;
      const int rB_ = half*16 + 8 + k;
      rowbuf[rA_][wp][0]=pA0; rowbuf[rA_][wp][1]=pA1; rowbuf[rA_][wp][2]=pA2;
      rowbuf[rA_][wp][3]=qA0; rowbuf[rA_][wp][4]=qA1; rowbuf[rA_][wp][5]=qA2;
      rowbuf[rB_][wp][0]=pB0; rowbuf[rB_][wp][1]=pB1; rowbuf[rB_][wp][2]=pB2;
      rowbuf[rB_][wp][3]=qB0; rowbuf[rB_][wp][4]=qB1; rowbuf[rB_][wp][5]=qB2;
    }

    xcA = nxA; rcA = nrA; xhA = nxhA; rhA = nrhA;
    xcB = nxB; rcB = nrB; xhB = nxhB; rhB = nrhB;
  }

  // ---- col stats: half 0 writes, half 1 accumulates, then stream out
  if (half == 0){
    *(float4*)&colbuf[0][c] = make_float4(cv0[0],cv0[1],cv0[2],cv0[3]);
    *(float4*)&colbuf[1][c] = make_float4(cv1[0],cv1[1],cv1[2],cv1[3]);
    *(float4*)&colbuf[2][c] = make_float4(cv2[0],cv2[1],cv2[2],cv2[3]);
    *(float4*)&colbuf[3][c] = make_float4(ch0[0],ch0[1],ch0[2],ch0[3]);
    *(float4*)&colbuf[4][c] = make_float4(ch1[0],ch1[1],ch1[2],ch1[3]);
    *(float4*)&colbuf[5][c] = make_float4(ch2[0],ch2[1],ch2[2],ch2[3]);
  }
  __syncthreads();
  if (half == 1){
    float4 t;
    t = *(float4*)&colbuf[0][c]; t.x+=cv0[0]; t.y+=cv0[1]; t.z+=cv0[2]; t.w+=cv0[3]; *(float4*)&colbuf[0][c]=t;
    t = *(float4*)&colbuf[1][c]; t.x+=cv1[0]; t.y+=cv1[1]; t.z+=cv1[2]; t.w+=cv1[3]; *(float4*)&colbuf[1][c]=t;
    t = *(float4*)&colbuf[2][c]; t.x+=cv2[0]; t.y+=cv2[1]; t.z+=cv2[2]; t.w+=cv2[3]; *(float4*)&colbuf[2][c]=t;
    t = *(float4*)&colbuf[3][c]; t.x+=ch0[0]; t.y+=ch0[1]; t.z+=ch0[2]; t.w+=ch0[3]; *(float4*)&colbuf[3][c]=t;
    t = *(float4*)&colbuf[4][c]; t.x+=ch1[0]; t.y+=ch1[1]; t.z+=ch1[2]; t.w+=ch1[3]; *(float4*)&colbuf[4][c]=t;
    t = *(float4*)&colbuf[5][c]; t.x+=ch2[0]; t.y+=ch2[1]; t.z+=ch2[2]; t.w+=ch2[3]; *(float4*)&colbuf[5][c]=t;
  }
  __syncthreads();
  {
    f32x4* slot = (f32x4*)(colPart + (size_t)bid * (6*512));
    const f32x4* cb = (const f32x4*)colbuf;
    #pragma unroll
    for (int i = 0; i < 3; ++i) slot[tid + 256*i] = cb[tid + 256*i];
  }

  // ---- row finalize: combine col-half pairs, cos, block sum (wave 0)
  if (tid < 64){
    float rv = 0.f, rh = 0.f;
    if (tid < 32){
      const float a0 = rowbuf[tid][0][0] + rowbuf[tid][1][0];
      const float a1 = rowbuf[tid][0][1] + rowbuf[tid][1][1];
      const float a2 = rowbuf[tid][0][2] + rowbuf[tid][1][2];
      const float b0 = rowbuf[tid][0][3] + rowbuf[tid][1][3];
      const float b1 = rowbuf[tid][0][4] + rowbuf[tid][1][4];
      const float b2 = rowbuf[tid][0][5] + rowbuf[tid][1][5];
      rv = cos_sim(a0,a1,a2);
      const int h = q*32 + tid;
      rh = (h < 511) ? cos_sim(b0,b1,b2) : 0.f;
    }
    rv = wave_dpp_sum(rv);
    rh = wave_dpp_sum(rh);
    if (tid == 63){
      rowPart[2*bid+0] = rv;
      rowPart[2*bid+1] = rh;
    }
  }
}

// ---------------- finish: reduce col partials over 16 slots ------------------
__global__ __launch_bounds__(256) void gp_cols(
    const float* __restrict__ colPart, double* __restrict__ dblk)
{
  const int p = blockIdx.x >> 1;
  const int f = blockIdx.x & 1;    // 0 = fv, 1 = fh
  const int tid = threadIdx.x;
  double acc = 0.0;
  for (int c = tid; c < 512; c += 256){
    float d = 0.f, a = 0.f, b = 0.f;
    #pragma unroll
    for (int s = 0; s < 16; ++s){
      const float* sp = colPart + ((size_t)(p*16 + s) * 6 + f*3) * 512;
      d += sp[c]; a += sp[512 + c]; b += sp[1024 + c];
    }
    acc += (double)cos_sim(d, a, b);   // fv col 511: cos(0,0,0)=0, harmless
  }
  #pragma unroll
  for (int m = 1; m < 64; m <<= 1) acc += __shfl_xor(acc, m, 64);
  __shared__ double ls[4];
  const int w = tid >> 6, l = tid & 63;
  if (l == 0) ls[w] = acc;
  __syncthreads();
  if (tid == 0) dblk[blockIdx.x] = ls[0] + ls[1] + ls[2] + ls[3];
}

__global__ __launch_bounds__(256) void gp_fin(
    const double* __restrict__ dblk, const float* __restrict__ rowPart,
    int nblk, float* __restrict__ out)
{
  const int tid = threadIdx.x;
  double rv = 0, rh = 0, cv = 0, ch = 0;
  for (int i = tid; i < nblk; i += 256){
    rv += (double)rowPart[2*i];
    rh += (double)rowPart[2*i+1];
  }
  for (int i = tid; i < 192; i += 256){
    if (i & 1) ch += dblk[i]; else cv += dblk[i];
  }
  #pragma unroll
  for (int m = 1; m < 64; m <<= 1){
    rv += __shfl_xor(rv, m, 64); rh += __shfl_xor(rh, m, 64);
    cv += __shfl_xor(cv, m, 64); ch += __shfl_xor(ch, m, 64);
  }
  __shared__ double ls[4][4];
  const int w = tid >> 6, l = tid & 63;
  if (l == 0){ ls[w][0]=rv; ls[w][1]=rh; ls[w][2]=cv; ls[w][3]=ch; }
  __syncthreads();
  if (tid == 0){
    double RV=0, RH=0, CV=0, CH=0;
    #pragma unroll
    for (int i = 0; i < 4; ++i){ RV+=ls[i][0]; RH+=ls[i][1]; CV+=ls[i][2]; CH+=ls[i][3]; }
    const double t = RV/512.0 + RH/511.0 + CV/511.0 + CH/512.0;
    out[0] = (float)(-t / 32.0);
  }
}

extern "C" void kernel_launch(void* const* d_in, const int* in_sizes, int n_in,
                              void* d_out, int out_size, void* d_ws, size_t ws_size,
                              hipStream_t stream) {
  const float* X = (const float*)d_in[0];
  const float* R = (const float*)d_in[1];
  float* out = (float*)d_out;

  float*  colPart = (float*)d_ws;                         // 96*16*6*512 f32
  float*  rowPart = colPart + (size_t)96*16*6*512;        // 1536*2 f32
  double* dblk    = (double*)(rowPart + (size_t)1536*2);  // 192 f64

  gp_uni <<<dim3(1536), dim3(256), 0, stream>>>(X, R, rowPart, colPart);
  gp_cols<<<dim3(192),  dim3(256), 0, stream>>>(colPart, dblk);
  gp_fin <<<dim3(1),    dim3(256), 0, stream>>>(dblk, rowPart, 1536, out);
}

// Round 13
// 52.695 us; speedup vs baseline: 2.3428x; 1.0181x over previous
//
#include <hip/hip_runtime.h>

// GPLoss: gradient-profile loss, scalar output.
// Main pass (R8 structure + depth-2 software pipeline): 1536 blocks x 256 thr;
// block = one 32-row band of one plane. Wave (half,wp): rows [h0,h0+16) x
// 256 cols, lane owns 4 cols (float4). Pipeline slots C/N/P: iteration k
// prefetches row h+2, computes f_v(C) + f_h(C,N) from data loaded one full
// iteration earlier -> load latency hidden under compute. Halo col via
// shfl_down (lane63/wp0 scalar only). Row stats: 6 DPP chains (VALU pipe);
// col stats: 24 per-thread accums -> 2-phase LDS merge -> colPart slot
// (96*16 = 18.9 MB, L3-safe: inputs stay resident across timed replays).
// ws: colPart f32[96*16][6][512] ; rowPart f32[1536][2] ; dblk f64[192]

typedef float f32x4 __attribute__((ext_vector_type(4)));

#define DPP_ADD(x, ctrl, rmask) \
  x += __int_as_float(__builtin_amdgcn_update_dpp(0, __float_as_int(x), ctrl, rmask, 0xf, false))

__device__ __forceinline__ float wave_dpp_sum(float x){
  DPP_ADD(x, 0x111, 0xf);   // row_shr:1
  DPP_ADD(x, 0x112, 0xf);   // row_shr:2
  DPP_ADD(x, 0x114, 0xf);   // row_shr:4
  DPP_ADD(x, 0x118, 0xf);   // row_shr:8
  DPP_ADD(x, 0x142, 0xa);   // row_bcast:15 -> rows 1,3
  DPP_ADD(x, 0x143, 0xc);   // row_bcast:31 -> rows 2,3
  return x;                 // lane 63 holds the 64-lane sum
}

__device__ __forceinline__ float cos_sim(float d, float sx, float sr){
  float nx = fmaxf(sqrtf(sx), 1e-12f);
  float nr = fmaxf(sqrtf(sr), 1e-12f);
  return d / (nx * nr);
}

__global__ __launch_bounds__(256) void gp_uni(
    const float* __restrict__ X, const float* __restrict__ R,
    float* __restrict__ rowPart, float* __restrict__ colPart)
{
  const int bid = blockIdx.x;
  const int p = bid >> 4, q = bid & 15;        // plane, 32-row band
  const int tid = threadIdx.x, w = tid >> 6, l = tid & 63;
  const int half = w >> 1;                      // rows [h0, h0+16)
  const int wp   = w & 1;                       // col half: wp*256
  const size_t plane = (size_t)p * (512u * 512u);
  const float* xp = X + plane;
  const float* rp = R + plane;
  const int c = wp*256 + 4*l;                   // cols c..c+3
  const bool tlast = (c == 508);                // col 511: no f_v
  const bool edge  = (l == 63) && (wp == 0);    // halo col 256 via scalar
  const int h0 = q*32 + half*16;

  __shared__ float colbuf[6][512];              // 12 KB band merge
  __shared__ float rowbuf[32][2][6];            // 1.5 KB row stats

  float cv0[4], cv1[4], cv2[4], ch0[4], ch1[4], ch2[4];
  #pragma unroll
  for (int j = 0; j < 4; ++j){
    cv0[j]=0.f; cv1[j]=0.f; cv2[j]=0.f;
    ch0[j]=0.f; ch1[j]=0.f; ch2[j]=0.f;
  }

  // ---- pipeline preamble: C = row h0, N = row h0+1
  const float* xr0 = xp + (size_t)h0*512;
  const float* rr0 = rp + (size_t)h0*512;
  float4 xC = *(const float4*)(xr0 + c), rC = *(const float4*)(rr0 + c);
  float xhC = 0.f, rhC = 0.f;
  if (edge){ xhC = xr0[256]; rhC = rr0[256]; }
  const float* xr1 = xp + (size_t)(h0+1)*512;
  const float* rr1 = rp + (size_t)(h0+1)*512;
  float4 xN = *(const float4*)(xr1 + c), rN = *(const float4*)(rr1 + c);
  float xhN = 0.f, rhN = 0.f;
  if (edge){ xhN = xr1[256]; rhN = rr1[256]; }

  for (int k = 0; k < 16; ++k){
    const int h  = h0 + k;
    const int hp = (h+2 < 512) ? h+2 : 511;     // prefetch row (clamped)

    // ---- issue prefetch P (consumed next iteration)
    const float* xrp_ = xp + (size_t)hp*512;
    const float* rrp_ = rp + (size_t)hp*512;
    const float4 xP = *(const float4*)(xrp_ + c);
    const float4 rP = *(const float4*)(rrp_ + c);
    float xhP = 0.f, rhP = 0.f;
    if (edge){ xhP = xrp_[256]; rhP = rrp_[256]; }

    // ---- halo col c+4 from neighbor lane (edge lane uses prefetched scalar)
    float xhalo = __shfl_down(xC.x, 1, 64);
    float rhalo = __shfl_down(rC.x, 1, 64);
    if (edge){ xhalo = xhC; rhalo = rhC; }

    // ---- compute from C (f_v) and C,N (f_h). h==511: N==C -> dh=0.
    const float ax[4] = {xC.x, xC.y, xC.z, xC.w};
    const float ar[4] = {rC.x, rC.y, rC.z, rC.w};
    const float bx[4] = {xN.x, xN.y, xN.z, xN.w};
    const float br[4] = {rN.x, rN.y, rN.z, rN.w};

    float dv[4], ev[4];
    dv[0]=ax[0]-ax[1]; dv[1]=ax[1]-ax[2]; dv[2]=ax[2]-ax[3];
    ev[0]=ar[0]-ar[1]; ev[1]=ar[1]-ar[2]; ev[2]=ar[2]-ar[3];
    dv[3] = tlast ? 0.f : (ax[3]-xhalo);
    ev[3] = tlast ? 0.f : (ar[3]-rhalo);

    float p0=0.f,p1=0.f,p2=0.f, q0=0.f,q1=0.f,q2=0.f;
    #pragma unroll
    for (int j = 0; j < 4; ++j){
      p0 = fmaf(dv[j],ev[j],p0); p1 = fmaf(dv[j],dv[j],p1); p2 = fmaf(ev[j],ev[j],p2);
      cv0[j] = fmaf(dv[j],ev[j],cv0[j]);
      cv1[j] = fmaf(dv[j],dv[j],cv1[j]);
      cv2[j] = fmaf(ev[j],ev[j],cv2[j]);
      const float dh = ax[j]-bx[j];
      const float eh = ar[j]-br[j];
      q0 = fmaf(dh,eh,q0); q1 = fmaf(dh,dh,q1); q2 = fmaf(eh,eh,q2);
      ch0[j] = fmaf(dh,eh,ch0[j]);
      ch1[j] = fmaf(dh,dh,ch1[j]);
      ch2[j] = fmaf(eh,eh,ch2[j]);
    }

    // ---- 6 independent DPP chains (VALU pipe)
    p0 = wave_dpp_sum(p0); p1 = wave_dpp_sum(p1); p2 = wave_dpp_sum(p2);
    q0 = wave_dpp_sum(q0); q1 = wave_dpp_sum(q1); q2 = wave_dpp_sum(q2);
    if (l == 63){
      const int rr_ = half*16 + k;
      rowbuf[rr_][wp][0]=p0; rowbuf[rr_][wp][1]=p1; rowbuf[rr_][wp][2]=p2;
      rowbuf[rr_][wp][3]=q0; rowbuf[rr_][wp][4]=q1; rowbuf[rr_][wp][5]=q2;
    }

    // ---- shift pipeline
    xC = xN; rC = rN; xhC = xhN; rhC = rhN;
    xN = xP; rN = rP; xhN = xhP; rhN = rhP;
  }

  // ---- col stats: half 0 writes, half 1 accumulates, then stream out
  if (half == 0){
    *(float4*)&colbuf[0][c] = make_float4(cv0[0],cv0[1],cv0[2],cv0[3]);
    *(float4*)&colbuf[1][c] = make_float4(cv1[0],cv1[1],cv1[2],cv1[3]);
    *(float4*)&colbuf[2][c] = make_float4(cv2[0],cv2[1],cv2[2],cv2[3]);
    *(float4*)&colbuf[3][c] = make_float4(ch0[0],ch0[1],ch0[2],ch0[3]);
    *(float4*)&colbuf[4][c] = make_float4(ch1[0],ch1[1],ch1[2],ch1[3]);
    *(float4*)&colbuf[5][c] = make_float4(ch2[0],ch2[1],ch2[2],ch2[3]);
  }
  __syncthreads();
  if (half == 1){
    float4 t;
    t = *(float4*)&colbuf[0][c]; t.x+=cv0[0]; t.y+=cv0[1]; t.z+=cv0[2]; t.w+=cv0[3]; *(float4*)&colbuf[0][c]=t;
    t = *(float4*)&colbuf[1][c]; t.x+=cv1[0]; t.y+=cv1[1]; t.z+=cv1[2]; t.w+=cv1[3]; *(float4*)&colbuf[1][c]=t;
    t = *(float4*)&colbuf[2][c]; t.x+=cv2[0]; t.y+=cv2[1]; t.z+=cv2[2]; t.w+=cv2[3]; *(float4*)&colbuf[2][c]=t;
    t = *(float4*)&colbuf[3][c]; t.x+=ch0[0]; t.y+=ch0[1]; t.z+=ch0[2]; t.w+=ch0[3]; *(float4*)&colbuf[3][c]=t;
    t = *(float4*)&colbuf[4][c]; t.x+=ch1[0]; t.y+=ch1[1]; t.z+=ch1[2]; t.w+=ch1[3]; *(float4*)&colbuf[4][c]=t;
    t = *(float4*)&colbuf[5][c]; t.x+=ch2[0]; t.y+=ch2[1]; t.z+=ch2[2]; t.w+=ch2[3]; *(float4*)&colbuf[5][c]=t;
  }
  __syncthreads();
  {
    f32x4* slot = (f32x4*)(colPart + (size_t)bid * (6*512));
    const f32x4* cb = (const f32x4*)colbuf;
    #pragma unroll
    for (int i = 0; i < 3; ++i) slot[tid + 256*i] = cb[tid + 256*i];
  }

  // ---- row finalize: combine col-half pairs, cos, block sum (wave 0)
  if (tid < 64){
    float rv = 0.f, rh = 0.f;
    if (tid < 32){
      const float a0 = rowbuf[tid][0][0] + rowbuf[tid][1][0];
      const float a1 = rowbuf[tid][0][1] + rowbuf[tid][1][1];
      const float a2 = rowbuf[tid][0][2] + rowbuf[tid][1][2];
      const float b0 = rowbuf[tid][0][3] + rowbuf[tid][1][3];
      const float b1 = rowbuf[tid][0][4] + rowbuf[tid][1][4];
      const float b2 = rowbuf[tid][0][5] + rowbuf[tid][1][5];
      rv = cos_sim(a0,a1,a2);
      const int h = q*32 + tid;
      rh = (h < 511) ? cos_sim(b0,b1,b2) : 0.f;
    }
    rv = wave_dpp_sum(rv);
    rh = wave_dpp_sum(rh);
    if (tid == 63){
      rowPart[2*bid+0] = rv;
      rowPart[2*bid+1] = rh;
    }
  }
}

// ---------------- finish: reduce col partials over 16 slots ------------------
__global__ __launch_bounds__(256) void gp_cols(
    const float* __restrict__ colPart, double* __restrict__ dblk)
{
  const int p = blockIdx.x >> 1;
  const int f = blockIdx.x & 1;    // 0 = fv, 1 = fh
  const int tid = threadIdx.x;
  double acc = 0.0;
  for (int c = tid; c < 512; c += 256){
    float d = 0.f, a = 0.f, b = 0.f;
    #pragma unroll
    for (int s = 0; s < 16; ++s){
      const float* sp = colPart + ((size_t)(p*16 + s) * 6 + f*3) * 512;
      d += sp[c]; a += sp[512 + c]; b += sp[1024 + c];
    }
    acc += (double)cos_sim(d, a, b);   // fv col 511: cos(0,0,0)=0, harmless
  }
  #pragma unroll
  for (int m = 1; m < 64; m <<= 1) acc += __shfl_xor(acc, m, 64);
  __shared__ double ls[4];
  const int w = tid >> 6, l = tid & 63;
  if (l == 0) ls[w] = acc;
  __syncthreads();
  if (tid == 0) dblk[blockIdx.x] = ls[0] + ls[1] + ls[2] + ls[3];
}

__global__ __launch_bounds__(256) void gp_fin(
    const double* __restrict__ dblk, const float* __restrict__ rowPart,
    int nblk, float* __restrict__ out)
{
  const int tid = threadIdx.x;
  double rv = 0, rh = 0, cv = 0, ch = 0;
  for (int i = tid; i < nblk; i += 256){
    rv += (double)rowPart[2*i];
    rh += (double)rowPart[2*i+1];
  }
  for (int i = tid; i < 192; i += 256){
    if (i & 1) ch += dblk[i]; else cv += dblk[i];
  }
  #pragma unroll
  for (int m = 1; m < 64; m <<= 1){
    rv += __shfl_xor(rv, m, 64); rh += __shfl_xor(rh, m, 64);
    cv += __shfl_xor(cv, m, 64); ch += __shfl_xor(ch, m, 64);
  }
  __shared__ double ls[4][4];
  const int w = tid >> 6, l = tid & 63;
  if (l == 0){ ls[w][0]=rv; ls[w][1]=rh; ls[w][2]=cv; ls[w][3]=ch; }
  __syncthreads();
  if (tid == 0){
    double RV=0, RH=0, CV=0, CH=0;
    #pragma unroll
    for (int i = 0; i < 4; ++i){ RV+=ls[i][0]; RH+=ls[i][1]; CV+=ls[i][2]; CH+=ls[i][3]; }
    const double t = RV/512.0 + RH/511.0 + CV/511.0 + CH/512.0;
    out[0] = (float)(-t / 32.0);
  }
}

extern "C" void kernel_launch(void* const* d_in, const int* in_sizes, int n_in,
                              void* d_out, int out_size, void* d_ws, size_t ws_size,
                              hipStream_t stream) {
  const float* X = (const float*)d_in[0];
  const float* R = (const float*)d_in[1];
  float* out = (float*)d_out;

  float*  colPart = (float*)d_ws;                         // 96*16*6*512 f32
  float*  rowPart = colPart + (size_t)96*16*6*512;        // 1536*2 f32
  double* dblk    = (double*)(rowPart + (size_t)1536*2);  // 192 f64

  gp_uni <<<dim3(1536), dim3(256), 0, stream>>>(X, R, rowPart, colPart);
  gp_cols<<<dim3(192),  dim3(256), 0, stream>>>(colPart, dblk);
  gp_fin <<<dim3(1),    dim3(256), 0, stream>>>(dblk, rowPart, 1536, out);
}